// Round 1
// baseline (44.450 us; speedup 1.0000x reference)
//
#include <hip/hip_runtime.h>

#define PAGE_SIZE 16

// One block per appended token. Each thread moves one float4 of the K row
// and one float4 of the V row into the paged cache. Mapping (searchsorted +
// page-table lookup) is computed per-thread from L1-resident index arrays.
__global__ __launch_bounds__(256) void kv_append_kernel(
    const float4* __restrict__ k,
    const float4* __restrict__ v,
    float4* __restrict__ out,
    const int* __restrict__ kv_append_indptr,
    const int* __restrict__ paged_kv_indptr,
    const int* __restrict__ paged_kv_indices,
    const int* __restrict__ last_page_len,
    int B, int nnz, int row_f4)
{
    int token = blockIdx.x;
    if (token >= nnz) return;

    // searchsorted(kv_append_indptr, token, side="right") - 1
    int b = B - 1;
    for (int i = 1; i < B; ++i) {
        if (token < kv_append_indptr[i]) { b = i - 1; break; }
    }
    int local      = token - kv_append_indptr[b];
    int np         = paged_kv_indptr[b + 1] - paged_kv_indptr[b];
    int seq_len    = (np > 0) ? ((np - 1) * PAGE_SIZE + last_page_len[b]) : 0;
    int append_len = kv_append_indptr[b + 1] - kv_append_indptr[b];
    int pos        = seq_len - append_len + local;            // >= 0 by construction
    int page_iter  = paged_kv_indptr[b] + pos / PAGE_SIZE;
    int page_id    = paged_kv_indices[page_iter];
    int off        = pos % PAGE_SIZE;

    size_t srow  = (size_t)token * row_f4;
    size_t drowk = ((size_t)page_id * 2 * PAGE_SIZE + off) * (size_t)row_f4;
    size_t drowv = drowk + (size_t)PAGE_SIZE * row_f4;

    for (int c = threadIdx.x; c < row_f4; c += blockDim.x) {
        out[drowk + c] = k[srow + c];
        out[drowv + c] = v[srow + c];
    }
}

extern "C" void kernel_launch(void* const* d_in, const int* in_sizes, int n_in,
                              void* d_out, int out_size, void* d_ws, size_t ws_size,
                              hipStream_t stream)
{
    const float* k  = (const float*)d_in[0];
    const float* v  = (const float*)d_in[1];
    // d_in[2] = kv_cache (zeros; fully overwritten by the scatter -> unused)
    const int* kv_append_indptr      = (const int*)d_in[3];
    const int* paged_kv_indptr       = (const int*)d_in[4];
    const int* paged_kv_indices      = (const int*)d_in[5];
    const int* paged_kv_last_page_len = (const int*)d_in[6];

    int B       = in_sizes[3] - 1;
    int n_pages = in_sizes[5];
    int HD      = in_sizes[2] / (n_pages * 2 * PAGE_SIZE);   // = H*D = 1024
    int row_f4  = HD / 4;                                    // = 256
    int nnz     = in_sizes[0] / HD;                          // = 16384

    dim3 grid(nnz), block(256);
    kv_append_kernel<<<grid, block, 0, stream>>>(
        (const float4*)k, (const float4*)v, (float4*)d_out,
        kv_append_indptr, paged_kv_indptr, paged_kv_indices,
        paged_kv_last_page_len, B, nnz, row_f4);
}